// Round 7
// baseline (493.011 us; speedup 1.0000x reference)
//
#include <hip/hip_runtime.h>
#include <hip/hip_fp16.h>

// GCN encoder:
//   Y1 = fp16(x @ W1)                   MFMA f16 (fp32 acc), [N,256]x[256,128]
//   Y2 = fp16(relu(b1 + spmm(Y1)) @ W2) spmm128 w/ FUSED matvec epilogue
//   out = b2 + spmm(Y2)                 (wave-per-row, F=64)
// spmm(x)@W == spmm(x@W) (linearity); biases folded into spmm accumulators.
//
// Pipeline (fast path, 4 dispatches):
//   prep (W1T cast, pk pack, cnt zero)
//   gemm_scatter = gemm1 MERGED WITH direct per-row slotted scatter:
//       slot = atomicAdd(&cnt[r],1); eb2[r*96+slot] = (col,val)
//       (cnt 400KB L2-resident; row slot cap 96 = 11+ sigma over Poisson(32);
//        spmm reads (start,len) = (row*96, cnt[row]) -- no scan, no sort)
//   spmm_fused -> spmm_csr64
//
// Round-3 lesson: spmm stays high-occupancy/low-LDS (TLP hides gather latency).
// Round-5 lesson: fp32 VALU GEMM had 1.28e7 LDS bank conflicts -> MFMA fp16.
// Round-6 lesson: millions of random global atomics ACCUMULATING VALUES
// write ~32B/op to HBM (bad). Counter atomics (no value traffic) are fine.
// Round-8/12 lesson: spmm gathers run at the per-CU random-gather ceiling
// (~12 B/cy/CU; 43% L2 miss at fp16 Y1 since 25.6MB >> 4MB/XCD L2).
// Round-14 lesson: grid-stride + w2s-amortization did NOT move spmm_fused
// (113us both ways) -- ceiling-bound, not overhead-bound.
// Round-15 lesson (counters): the two-level CSR build cost ~235us
// (partition 2x LDS-atomic passes; fine_scatter 209 blocks latency-bound
// scan+scatter, VALUBusy 5.6%, Occ 28%). Slotted per-row layout deletes
// both; one counter-atomic pass replaces them.
// Round-11 lesson: __shfl under a per-lane predicate exec-masks ds_bpermute;
// issue shuffles with full EXEC, mask the RESULT.
// Round-10 lesson: barrier-less wave-synchronous LDS handoff requires plain
// element-type stores (type-punned wide stores get TBAA-reordered).

#define PCHUNK 8192  // edges per scatter block (256 thr x 32)
#define EPT 32       // edges per thread in scatter
#define ROWCAP 96    // per-row edge slot (Poisson(32): P(>96)~1e-18/row)

typedef _Float16 half8 __attribute__((ext_vector_type(8)));
typedef _Float16 h2t __attribute__((ext_vector_type(2)));
typedef float floatx4 __attribute__((ext_vector_type(4)));

// ---------------------------------------------------------------- weight prep (fast path)
// W1T[n][k] = fp16(W1[k][n]); pk[kk*64+c] = (W2[2kk][c], W2[2kk+1][c]) fp16
// tail threads: zero cnt (per-row slot cursors)
__global__ __launch_bounds__(256) void prep_weights_kernel(const float* __restrict__ W1,
                                                           const float* __restrict__ W2,
                                                           __half* __restrict__ W1T,
                                                           h2t* __restrict__ pk,
                                                           int* __restrict__ cnt, int nN) {
    int i = blockIdx.x * 256 + threadIdx.x;
    if (i < 256 * 128) {
        int k = i >> 7, n = i & 127;
        W1T[n * 256 + k] = __float2half_rn(W1[i]);
    } else if (i < 256 * 128 + 4096) {
        int j = i - 256 * 128;
        int kk = j >> 6, c = j & 63;
        h2t v;
        v[0] = (_Float16)W2[(2 * kk) * 64 + c];
        v[1] = (_Float16)W2[(2 * kk + 1) * 64 + c];
        pk[j] = v;
    } else {
        int j = i - (256 * 128 + 4096);
        if (j < nN) cnt[j] = 0;
    }
}

// ---------------------------------------------------------------- W transpose+cast (fallback)
__global__ __launch_bounds__(256) void transpose_w_kernel(const float* __restrict__ W,
                                                          __half* __restrict__ WT,
                                                          int K, int N) {
    int i = blockIdx.x * 256 + threadIdx.x;
    if (i < K * N) {
        int k = i / N, n = i % N;
        WT[n * K + k] = __float2half_rn(W[i]);
    }
}

// ---------------------------------------------------------------- MERGED gemm1 || scatter
// blocks [0, scblocks): direct per-row slotted scatter (no LDS):
//   slot = atomicAdd(&cnt[r],1); if (slot<ROWCAP) eb2[r*ROWCAP+slot]=(col,val)
// blocks [scblocks, ...): MFMA fp16 gemm Y1 = fp16(x @ W1), MT=64, KT=32,
//   NN=128, KK=256. Dynamic LDS = (64+128)*40*2 = 15360 B -> 8 blocks/CU.
__global__ __launch_bounds__(256) void gemm_scatter_kernel(
    const float* __restrict__ A, const __half* __restrict__ BT,
    __half* __restrict__ C, int nrows,
    const int* __restrict__ rows, const int* __restrict__ cols,
    const float* __restrict__ vals, int* __restrict__ cnt,
    int2* __restrict__ eb2, int nE, int scblocks) {
    extern __shared__ char smem[];
    const int t = threadIdx.x;

    if ((int)blockIdx.x < scblocks) {
        // ---------------- scatter branch (no LDS) ----------------
        const int c0 = blockIdx.x * PCHUNK;
#pragma unroll 4
        for (int j = 0; j < EPT; ++j) {
            int e = c0 + t + 256 * j;
            if (e < nE) {
                int r = rows[e];
                int slot = atomicAdd(&cnt[r], 1);
                if (slot < ROWCAP)  // overflow guard (P ~ 1e-13 dataset-wide)
                    eb2[(size_t)r * ROWCAP + slot] =
                        make_int2(cols[e], __float_as_int(vals[e]));
            }
        }
    } else {
        // ---------------- gemm branch (MT=64, KT=32, NN=128, KK=256) --------
        constexpr int MT = 64, KT = 32, KP = KT + 8, NN = 128, KK = 256;
        constexpr int WCT = NN / 32;
        __half* As = (__half*)smem;   // MT*KP
        __half* Bs = As + MT * KP;    // NN*KP
        const int wid = t >> 6, lane = t & 63;
        const int row0 = ((int)blockIdx.x - scblocks) * MT;
        const int wr = wid & 1, wc = wid >> 1;
        const int lrow = lane & 15, q = lane >> 4;

        floatx4 acc[2][WCT];
#pragma unroll
        for (int rt = 0; rt < 2; ++rt)
#pragma unroll
            for (int ct = 0; ct < WCT; ++ct)
#pragma unroll
                for (int i = 0; i < 4; ++i) acc[rt][ct][i] = 0.f;

        for (int kt = 0; kt < KK; kt += KT) {
            // As: 64 rows x 32 halves = 512 ushort4; 2 per thread
#pragma unroll
            for (int it = 0; it < MT * KT / 4 / 256; ++it) {
                int i4 = it * 256 + t;
                int m = i4 >> 3;
                int kk = (i4 & 7) << 2;
                int gr = row0 + m;
                float4 v = make_float4(0.f, 0.f, 0.f, 0.f);
                if (gr < nrows) v = *(const float4*)(A + (size_t)gr * KK + kt + kk);
                __half h0 = __float2half_rn(v.x), h1 = __float2half_rn(v.y);
                __half h2 = __float2half_rn(v.z), h3 = __float2half_rn(v.w);
                ushort4 u = make_ushort4(*(unsigned short*)&h0, *(unsigned short*)&h1,
                                         *(unsigned short*)&h2, *(unsigned short*)&h3);
                *(ushort4*)(As + m * KP + kk) = u;
            }
            // Bs: 128 rows x 32 halves = 1024 ushort4; 4 per thread
#pragma unroll
            for (int it = 0; it < NN * KT / 4 / 256; ++it) {
                int i4 = it * 256 + t;
                int n = i4 >> 3;
                int kk = (i4 & 7) << 2;
                *(ushort4*)(Bs + n * KP + kk) =
                    *(const ushort4*)(BT + (size_t)n * KK + kt + kk);
            }
            __syncthreads();

            half8 a0 = *(half8*)(As + (wr * 32 + lrow) * KP + q * 8);
            half8 a1 = *(half8*)(As + (wr * 32 + 16 + lrow) * KP + q * 8);
#pragma unroll
            for (int ct = 0; ct < WCT; ++ct) {
                half8 b = *(half8*)(Bs + (wc * (NN / 2) + ct * 16 + lrow) * KP + q * 8);
                acc[0][ct] = __builtin_amdgcn_mfma_f32_16x16x32_f16(a0, b, acc[0][ct], 0, 0, 0);
                acc[1][ct] = __builtin_amdgcn_mfma_f32_16x16x32_f16(a1, b, acc[1][ct], 0, 0, 0);
            }
            __syncthreads();
        }

#pragma unroll
        for (int rt = 0; rt < 2; ++rt)
#pragma unroll
            for (int ct = 0; ct < WCT; ++ct)
#pragma unroll
                for (int r = 0; r < 4; ++r) {
                    int gr = row0 + wr * 32 + rt * 16 + q * 4 + r;
                    if (gr < nrows)
                        C[(size_t)gr * NN + wc * (NN / 2) + ct * 16 + lrow] =
                            __float2half_rn(acc[rt][ct][r]);
                }
    }
}

// ---------------------------------------------------------------- FUSED spmm128 + matvec
// Grid-stride wave-per-row over slotted eb2 (start=row*ROWCAP, len=cnt[row]).
// Gather: lane = (edge-subgroup g = lane>>4, feature-group fg = lane&15);
// one dwordx4 load covers 4 edges' rows. shfl_xor(16,32) combines subgroups;
// bias+relu; pack to per-wave LDS (plain h2t stores); per-row matvec by W2.
__global__ __launch_bounds__(256) void spmm_fused_kernel(const int* __restrict__ cnt,
                                                         const int2* __restrict__ eb,
                                                         const __half* __restrict__ Y,
                                                         const float* __restrict__ b1,
                                                         const h2t* __restrict__ pk,
                                                         __half* __restrict__ Y2, int nN) {
    __shared__ h2t w2s[64 * 64];  // w2s[kk*64+c] = (W2[2kk][c], W2[2kk+1][c])
    __shared__ h2t hs[4][64];     // per-wave relu'd H1 row, packed pairs
    const int t = threadIdx.x;
#pragma unroll
    for (int i = 0; i < 16; ++i) w2s[i * 256 + t] = pk[i * 256 + t];
    __syncthreads();

    const int wv = t >> 6;
    const int lane = t & 63;
    const int fg = lane & 15;  // feature group: 8 halfs at fg*8
    const int g = lane >> 4;   // edge subgroup 0..3
    const int gw = blockIdx.x * 4 + wv;
    const int nw = gridDim.x * 4;

    for (int row = gw; row < nN; row += nw) {
        float acc[8];
#pragma unroll
        for (int p = 0; p < 8; ++p) acc[p] = 0.f;

        int len = cnt[row];
        if (len > ROWCAP) len = ROWCAP;
        int s = row * ROWCAP;
        int e1 = s + len;
        for (int base = s; base < e1; base += 64) {
            int n = min(64, e1 - base);
            int2 my = (lane < n) ? eb[base + lane] : make_int2(0, 0);
            for (int j = 0; j < n; j += 8) {
                int i0 = j + g;
                int i1 = j + 4 + g;
                // clamp invalid subgroup indices onto edge j (same cache
                // lines, valid source lane); contribution zeroed via val.
                int s0 = (i0 < n) ? i0 : j;
                int s1 = (i1 < n) ? i1 : j;
                // UNCONDITIONAL shuffles (full EXEC); mask results after.
                int c0 = __shfl(my.x, s0);
                int c1 = __shfl(my.x, s1);
                float v0 = __int_as_float(__shfl(my.y, s0));
                float v1 = __int_as_float(__shfl(my.y, s1));
                if (i0 >= n) v0 = 0.f;
                if (i1 >= n) v1 = 0.f;
                half8 y0 = *(const half8*)(Y + ((size_t)c0 << 7) + (fg << 3));
                half8 y1 = *(const half8*)(Y + ((size_t)c1 << 7) + (fg << 3));
#pragma unroll
                for (int p = 0; p < 8; ++p) acc[p] = fmaf(v0, (float)y0[p], acc[p]);
#pragma unroll
                for (int p = 0; p < 8; ++p) acc[p] = fmaf(v1, (float)y1[p], acc[p]);
            }
        }
        // combine the 4 edge-subgroups (lanes differ in bits 4,5 only)
#pragma unroll
        for (int p = 0; p < 8; ++p) acc[p] += __shfl_xor(acc[p], 16);
#pragma unroll
        for (int p = 0; p < 8; ++p) acc[p] += __shfl_xor(acc[p], 32);

        // bias + relu + pack into per-wave LDS. PLAIN element-type (h2t)
        // stores only (barrier-less wave-synchronous handoff).
        if (g == 0) {
            floatx4 ba = *(const floatx4*)(b1 + fg * 8);
            floatx4 bb = *(const floatx4*)(b1 + fg * 8 + 4);
            float f[8];
#pragma unroll
            for (int p = 0; p < 4; ++p) f[p] = fmaxf(acc[p] + ba[p], 0.f);
#pragma unroll
            for (int p = 0; p < 4; ++p) f[4 + p] = fmaxf(acc[4 + p] + bb[p], 0.f);
#pragma unroll
            for (int p = 0; p < 4; ++p) {
                h2t pr;
                pr[0] = (_Float16)f[2 * p];
                pr[1] = (_Float16)f[2 * p + 1];
                hs[wv][fg * 4 + p] = pr;  // hs[wv][i] = features (2i, 2i+1)
            }
        }
        __builtin_amdgcn_sched_barrier(0);  // pin handoff order

        // matvec: o = sum_kk dot2(hs[kk], W2pair[kk][lane])
        // (same-wave DS ordering: no barrier needed)
        float o = 0.f;
#pragma unroll 8
        for (int kk = 0; kk < 64; ++kk) {
            h2t a = hs[wv][kk];           // LDS broadcast (free)
            h2t b = w2s[kk * 64 + lane];  // 2-way bank aliasing (free)
#if __has_builtin(__builtin_amdgcn_fdot2)
            o = __builtin_amdgcn_fdot2(a, b, o, false);
#else
            o = fmaf((float)a[0], (float)b[0], o);
            o = fmaf((float)a[1], (float)b[1], o);
#endif
        }
        Y2[(size_t)row * 64 + lane] = __float2half_rn(o);
    }
}

// ---------------------------------------------------------------- spmm F=64 (final layer)
// Grid-stride wave-per-row over slotted eb2; 8-lanes-per-edge dwordx4 gather
// (one load = 8 edges' 128B rows); acc[8]; shfl_xor(8,16,32) combines
// subgroups; lanes 0..7 write 256B coalesced fp32.
__global__ __launch_bounds__(256) void spmm_csr64_kernel(const int* __restrict__ cnt,
                                                         const int2* __restrict__ eb,
                                                         const __half* __restrict__ Y,
                                                         const float* __restrict__ bias,
                                                         float* __restrict__ out, int nN) {
    const int lane = threadIdx.x & 63;
    const int fg = lane & 7;  // 8 features at fg*8
    const int g = lane >> 3;  // edge subgroup 0..7
    const int gw = blockIdx.x * 4 + (threadIdx.x >> 6);
    const int nw = gridDim.x * 4;

    for (int row = gw; row < nN; row += nw) {
        float acc[8];
#pragma unroll
        for (int p = 0; p < 8; ++p) acc[p] = 0.f;

        int len = cnt[row];
        if (len > ROWCAP) len = ROWCAP;
        int s = row * ROWCAP;
        int e1 = s + len;
        for (int base = s; base < e1; base += 64) {
            int n = min(64, e1 - base);
            int2 my = (lane < n) ? eb[base + lane] : make_int2(0, 0);
            for (int j = 0; j < n; j += 16) {
                int i0 = j + g;
                int i1 = j + 8 + g;
                int s0 = (i0 < n) ? i0 : j;
                int s1 = (i1 < n) ? i1 : j;
                int c0 = __shfl(my.x, s0);
                int c1 = __shfl(my.x, s1);
                float v0 = __int_as_float(__shfl(my.y, s0));
                float v1 = __int_as_float(__shfl(my.y, s1));
                if (i0 >= n) v0 = 0.f;
                if (i1 >= n) v1 = 0.f;
                half8 y0 = *(const half8*)(Y + ((size_t)c0 << 6) + (fg << 3));
                half8 y1 = *(const half8*)(Y + ((size_t)c1 << 6) + (fg << 3));
#pragma unroll
                for (int p = 0; p < 8; ++p) acc[p] = fmaf(v0, (float)y0[p], acc[p]);
#pragma unroll
                for (int p = 0; p < 8; ++p) acc[p] = fmaf(v1, (float)y1[p], acc[p]);
            }
        }
        // combine the 8 edge-subgroups (lanes differ in bits 3,4,5 only)
#pragma unroll
        for (int p = 0; p < 8; ++p) acc[p] += __shfl_xor(acc[p], 8);
#pragma unroll
        for (int p = 0; p < 8; ++p) acc[p] += __shfl_xor(acc[p], 16);
#pragma unroll
        for (int p = 0; p < 8; ++p) acc[p] += __shfl_xor(acc[p], 32);

        if (g == 0) {
            floatx4 ba = *(const floatx4*)(bias + fg * 8);
            floatx4 bb = *(const floatx4*)(bias + fg * 8 + 4);
            floatx4 o0, o1;
#pragma unroll
            for (int p = 0; p < 4; ++p) o0[p] = acc[p] + ba[p];
#pragma unroll
            for (int p = 0; p < 4; ++p) o1[p] = acc[4 + p] + bb[p];
            float* op = out + (size_t)row * 64 + fg * 8;
            *(floatx4*)op = o0;
            *(floatx4*)(op + 4) = o1;
        }
    }
}

// ---------------------------------------------------------------- fallback atomic path
__global__ __launch_bounds__(256) void init_bias_kernel(float* __restrict__ out,
                                                        const float* __restrict__ bias,
                                                        int fmask, size_t total) {
    size_t i = (size_t)blockIdx.x * 256 + threadIdx.x;
    if (i < total) out[i] = bias[i & fmask];
}

template <int F>
__global__ __launch_bounds__(256) void spmm_atomic_kernel(const int* __restrict__ rows,
                                                          const int* __restrict__ cols,
                                                          const float* __restrict__ vals,
                                                          const __half* __restrict__ Y,
                                                          float* __restrict__ out, int nE) {
    int e = blockIdx.x * 4 + (threadIdx.x >> 6);
    if (e >= nE) return;
    int lane = threadIdx.x & 63;
    int r = rows[e];
    int c = cols[e];
    float v = vals[e];
    if (F == 128) {
        float2 y = __half22float2(*((const __half2*)(Y + (size_t)c * 128) + lane));
        float* op = out + (size_t)r * 128 + lane * 2;
        unsafeAtomicAdd(op, v * y.x);
        unsafeAtomicAdd(op + 1, v * y.y);
    } else {
        float y = __half2float(Y[(size_t)c * F + lane]);
        unsafeAtomicAdd(out + (size_t)r * F + lane, v * y);
    }
}

// ---------------------------------------------------------------- MFMA fp16 GEMM (fallback)
// C[nrows,NN] (fp16) = (RELU_IN ? relu(A) : A)[nrows,KK] (fp32) @ B[KK,NN]
template <int NN, int KK, bool RELU_IN>
__global__ __launch_bounds__(256) void gemm_mfma_kernel(const float* __restrict__ A,
                                                        const __half* __restrict__ BT,
                                                        __half* __restrict__ C, int nrows) {
    constexpr int MT = 64, KT = 64, KP = KT + 8;
    __shared__ __half As[MT * KP];
    __shared__ __half Bs[NN * KP];
    const int tid = threadIdx.x;
    const int wid = tid >> 6, lane = tid & 63;
    const int row0 = blockIdx.x * MT;
    const int wr = wid & 1, wc = wid >> 1;
    constexpr int WCT = NN / 32;
    const int lrow = lane & 15, q = lane >> 4;

    floatx4 acc[2][WCT];
#pragma unroll
    for (int rt = 0; rt < 2; ++rt)
#pragma unroll
        for (int ct = 0; ct < WCT; ++ct)
#pragma unroll
            for (int i = 0; i < 4; ++i) acc[rt][ct][i] = 0.f;

    for (int kt = 0; kt < KK; kt += KT) {
#pragma unroll
        for (int it = 0; it < MT * KT / 4 / 256; ++it) {
            int i4 = it * 256 + tid;
            int m = i4 >> 4;
            int kk = (i4 & 15) << 2;
            int gr = row0 + m;
            float4 v = make_float4(0.f, 0.f, 0.f, 0.f);
            if (gr < nrows) v = *(const float4*)(A + (size_t)gr * KK + kt + kk);
            if (RELU_IN) {
                v.x = fmaxf(v.x, 0.f); v.y = fmaxf(v.y, 0.f);
                v.z = fmaxf(v.z, 0.f); v.w = fmaxf(v.w, 0.f);
            }
            __half h0 = __float2half_rn(v.x), h1 = __float2half_rn(v.y);
            __half h2 = __float2half_rn(v.z), h3 = __float2half_rn(v.w);
            ushort4 u = make_ushort4(*(unsigned short*)&h0, *(unsigned short*)&h1,
                                     *(unsigned short*)&h2, *(unsigned short*)&h3);
            *(ushort4*)(As + m * KP + kk) = u;
        }
#pragma unroll
        for (int it = 0; it < NN * KT / 4 / 256; ++it) {
            int i4 = it * 256 + tid;
            int n = i4 >> 4;
            int kk = (i4 & 15) << 2;
            *(ushort4*)(Bs + n * KP + kk) =
                *(const ushort4*)(BT + (size_t)n * KK + kt + kk);
        }
        __syncthreads();

#pragma unroll
        for (int ks = 0; ks < KT; ks += 32) {
            half8 a0 = *(half8*)(As + (wr * 32 + lrow) * KP + ks + q * 8);
            half8 a1 = *(half8*)(As + (wr * 32 + 16 + lrow) * KP + ks + q * 8);
#pragma unroll
            for (int ct = 0; ct < WCT; ++ct) {
                half8 b = *(half8*)(Bs + (wc * (NN / 2) + ct * 16 + lrow) * KP + ks + q * 8);
                acc[0][ct] = __builtin_amdgcn_mfma_f32_16x16x32_f16(a0, b, acc[0][ct], 0, 0, 0);
                acc[1][ct] = __builtin_amdgcn_mfma_f32_16x16x32_f16(a1, b, acc[1][ct], 0, 0, 0);
            }
        }
        __syncthreads();
    }

#pragma unroll
    for (int rt = 0; rt < 2; ++rt)
#pragma unroll
        for (int ct = 0; ct < WCT; ++ct)
#pragma unroll
            for (int r = 0; r < 4; ++r) {
                int gr = row0 + wr * 32 + rt * 16 + q * 4 + r;
                if (gr < nrows)
                    C[(size_t)gr * NN + wc * (NN / 2) + ct * 16 + lrow] =
                        __float2half_rn(acc[rt][ct][r]);
            }
}

extern "C" void kernel_launch(void* const* d_in, const int* in_sizes, int n_in,
                              void* d_out, int out_size, void* d_ws, size_t ws_size,
                              hipStream_t stream) {
    const float* x    = (const float*)d_in[0];
    const int*   rows = (const int*)d_in[1];
    const int*   cols = (const int*)d_in[2];
    const float* vals = (const float*)d_in[3];
    const float* W1   = (const float*)d_in[4];
    const float* b1   = (const float*)d_in[5];
    const float* W2   = (const float*)d_in[6];
    const float* b2   = (const float*)d_in[7];
    float* out = (float*)d_out;

    const int nN = in_sizes[0] / 256;  // 100000
    const int nE = in_sizes[1];        // 3200000

    const int mblocks  = (nN + 63) / 64;
    const int scblocks = (nE + PCHUNK - 1) / PCHUNK;
    const int sblocks  = min(2048, (nN + 3) / 4);  // grid-stride spmm
    const int eblocks4 = (nE + 3) / 4;

    // ---- fast-path ws layout (slotted per-row edges; no eb1, no off2) ----
    char* w = (char*)d_ws;
    __half* Y1h = (__half*)w;  w += (size_t)nN * 128 * 2;
    __half* Y2h = (__half*)w;  w += (size_t)nN * 64 * 2;
    __half* W1T = (__half*)w;  w += (size_t)256 * 128 * 2;
    h2t*    pk  = (h2t*)w;     w += (size_t)4096 * 4;
    int*    cnt = (int*)w;     w += (size_t)nN * 4;
    int2*   eb2 = (int2*)w;    w += (size_t)nN * ROWCAP * 8;
    size_t need = (size_t)(w - (char*)d_ws);

    if (ws_size >= need && nN <= (1 << 17)) {
        // ---- fast path (4 dispatches) ----
        prep_weights_kernel<<<(256 * 128 + 4096 + nN + 255) / 256, 256, 0, stream>>>(
            W1, W2, W1T, pk, cnt, nN);

        // gemm1 || direct scatter (independent; scatter blocks first so the
        // spmm dependency chain clears earliest). Dynamic LDS 15360 B.
        gemm_scatter_kernel<<<scblocks + mblocks, 256, (64 + 128) * 40 * 2, stream>>>(
            x, W1T, Y1h, nN, rows, cols, vals, cnt, eb2, nE, scblocks);

        // Y2 = fp16(relu(b1 + spmm(Y1)) @ W2)   [fused]
        spmm_fused_kernel<<<sblocks, 256, 0, stream>>>(cnt, eb2, Y1h, b1, pk, Y2h, nN);
        // out = b2 + spmm(Y2)
        spmm_csr64_kernel<<<sblocks, 256, 0, stream>>>(cnt, eb2, Y2h, b2, out, nN);
    } else {
        // ---- fallback: atomic path (own ws layout) ----
        char* v = (char*)d_ws;
        __half* fY1h = (__half*)v;  v += (size_t)nN * 128 * 2;
        float*  fH1  = (float*)v;   v += (size_t)nN * 128 * 4;
        __half* fW1T = (__half*)v;  v += (size_t)256 * 128 * 2;
        __half* fW2T = (__half*)v;  v += (size_t)128 * 64 * 2;

        transpose_w_kernel<<<(256 * 128 + 255) / 256, 256, 0, stream>>>(W1, fW1T, 256, 128);
        transpose_w_kernel<<<(128 * 64 + 255) / 256, 256, 0, stream>>>(W2, fW2T, 128, 64);
        gemm_mfma_kernel<128, 256, false><<<mblocks, 256, 0, stream>>>(x, fW1T, fY1h, nN);
        size_t totH1 = (size_t)nN * 128;
        init_bias_kernel<<<(int)((totH1 + 255) / 256), 256, 0, stream>>>(fH1, b1, 127, totH1);
        spmm_atomic_kernel<128><<<eblocks4, 256, 0, stream>>>(rows, cols, vals, fY1h, fH1, nE);
        gemm_mfma_kernel<64, 128, true><<<mblocks, 256, 0, stream>>>(fH1, fW2T, fY1h, nN);
        size_t totOut = (size_t)nN * 64;
        init_bias_kernel<<<(int)((totOut + 255) / 256), 256, 0, stream>>>(out, b2, 63, totOut);
        spmm_atomic_kernel<64><<<eblocks4, 256, 0, stream>>>(rows, cols, vals, fY1h, out, nE);
    }
}

// Round 8
// 444.036 us; speedup vs baseline: 1.1103x; 1.1103x over previous
//
#include <hip/hip_runtime.h>
#include <hip/hip_fp16.h>

// GCN encoder:
//   Y1 = fp16(x @ W1)                   MFMA f16 (fp32 acc), [N,256]x[256,128]
//   Y2 = fp16(relu(b1 + spmm(Y1)) @ W2) spmm128 w/ FUSED matvec epilogue
//   out = b2 + spmm(Y2)                 (wave-per-row, F=64)
// spmm(x)@W == spmm(x@W) (linearity); biases folded into spmm accumulators.
//
// Pipeline (fast path, 5 dispatches):
//   prep -> gemm_part (gemm1 || coarse partition) -> fine_scatter
//        -> spmm_fused -> spmm_csr64
//
// Round-3 lesson: spmm stays high-occupancy/low-LDS (TLP hides gather latency).
// Round-5 lesson: fp32 VALU GEMM had 1.28e7 LDS bank conflicts -> MFMA fp16.
// Round-6+16 lesson: random small-payload scatter to a >L2 region amplifies
// to 64B lines (round-16: 3.2M x 8B -> 223MB WRITE, 192us). The coarse-bucket
// intermediate keeps scatter runs fat / L2-windowed; it cannot be skipped.
// Counter atomics alone are fine; payload scatter is what amplifies.
// Round-8/12 lesson: spmm gathers run at the per-CU random-gather ceiling
// (~12 B/cy/CU; 43% L2 miss at fp16 Y1 since 25.6MB >> 4MB/XCD L2).
// Round-14 lesson: grid-stride + w2s-amortization did NOT move spmm_fused
// (113us both ways) -- ceiling-bound, not overhead-bound.
// Round-15 lesson: two-level build was ~235us; fine_scatter latency-bound at
// 209 blocks (0.8/CU). Round-17: RPB 480->240 (417 blocks) + gemm KT=32
// (19.4KB/block -> more co-residency for partition blocks).
// Round-11 lesson: __shfl under a per-lane predicate exec-masks ds_bpermute;
// issue shuffles with full EXEC, mask the RESULT.
// Round-10 lesson: barrier-less wave-synchronous LDS handoff requires plain
// element-type stores (type-punned wide stores get TBAA-reordered).

#define RPB 240      // rows per coarse bucket (rowlocal < 2^15 payload limit)
#define NB_MAX 512   // max buckets
#define PCHUNK 8192  // edges per partition block (256 thr x 32)
#define EPT 32       // edges per thread in partition
#define CAPE 9216    // per-bucket slot capacity (mean 7673 + ~17 sigma)

typedef _Float16 half8 __attribute__((ext_vector_type(8)));
typedef _Float16 h2t __attribute__((ext_vector_type(2)));
typedef float floatx4 __attribute__((ext_vector_type(4)));

// ---------------------------------------------------------------- weight prep (fast path)
// W1T[n][k] = fp16(W1[k][n]); pk[kk*64+c] = (W2[2kk][c], W2[2kk+1][c]) fp16
// tail threads: zero gcnt (partition's slot cursors)
__global__ __launch_bounds__(256) void prep_weights_kernel(const float* __restrict__ W1,
                                                           const float* __restrict__ W2,
                                                           __half* __restrict__ W1T,
                                                           h2t* __restrict__ pk,
                                                           int* __restrict__ gcnt) {
    int i = blockIdx.x * 256 + threadIdx.x;
    if (i < 256 * 128) {
        int k = i >> 7, n = i & 127;
        W1T[n * 256 + k] = __float2half_rn(W1[i]);
    } else if (i < 256 * 128 + 4096) {
        int j = i - 256 * 128;
        int kk = j >> 6, c = j & 63;
        h2t v;
        v[0] = (_Float16)W2[(2 * kk) * 64 + c];
        v[1] = (_Float16)W2[(2 * kk + 1) * 64 + c];
        pk[j] = v;
    } else {
        int j = i - (256 * 128 + 4096);
        if (j < NB_MAX) gcnt[j] = 0;
    }
}

// ---------------------------------------------------------------- W transpose+cast (fallback)
__global__ __launch_bounds__(256) void transpose_w_kernel(const float* __restrict__ W,
                                                          __half* __restrict__ WT,
                                                          int K, int N) {
    int i = blockIdx.x * 256 + threadIdx.x;
    if (i < K * N) {
        int k = i / N, n = i % N;
        WT[n * K + k] = __float2half_rn(W[i]);
    }
}

// ---------------------------------------------------------------- MERGED gemm1 || partition
// blocks [0, pblocks): coarse multisplit partition into per-bucket CAPE slots
//   (payload: col | rowlocal<<17, val; gcnt[b] = cursor/count).
// blocks [pblocks, ...): MFMA fp16 gemm Y1 = fp16(x @ W1), MT=64, KT=32,
//   NN=128, KK=256. Dynamic LDS = (64+128)*40*2 = 15360 B (+4KB static).
__global__ __launch_bounds__(256) void gemm_part_kernel(
    const float* __restrict__ A, const __half* __restrict__ BT,
    __half* __restrict__ C, int nrows,
    const int* __restrict__ rows, const int* __restrict__ cols,
    const float* __restrict__ vals, int* __restrict__ gcnt,
    int2* __restrict__ eb1, int nE, int nB, int pblocks) {
    extern __shared__ char smem[];
    __shared__ int hist[NB_MAX];
    __shared__ int cur[NB_MAX];
    const int t = threadIdx.x;

    if ((int)blockIdx.x < pblocks) {
        // ---------------- partition branch ----------------
        const int c0 = blockIdx.x * PCHUNK;
        for (int b = t; b < nB; b += 256) hist[b] = 0;
        __syncthreads();
        int myr[EPT];
#pragma unroll
        for (int j = 0; j < EPT; ++j) {
            int e = c0 + t + 256 * j;
            int r = (e < nE) ? rows[e] : -1;
            myr[j] = r;
            if (r >= 0) atomicAdd(&hist[r / RPB], 1);
        }
        __syncthreads();
        for (int b = t; b < nB; b += 256) {
            int c = hist[b];
            cur[b] = c ? b * CAPE + atomicAdd(&gcnt[b], c) : 0;
        }
        __syncthreads();
#pragma unroll
        for (int j = 0; j < EPT; ++j) {
            int r = myr[j];
            if (r >= 0) {
                int e = c0 + t + 256 * j;
                int bk = r / RPB;
                int rl = r - bk * RPB;
                int pos = atomicAdd(&cur[bk], 1);
                if (pos < bk * CAPE + CAPE)  // slot-overflow guard
                    eb1[pos] = make_int2((cols[e] & 0x1FFFF) | (rl << 17),
                                         __float_as_int(vals[e]));
            }
        }
    } else {
        // ---------------- gemm branch (MT=64, KT=32, NN=128, KK=256) --------
        constexpr int MT = 64, KT = 32, KP = KT + 8, NN = 128, KK = 256;
        constexpr int WCT = NN / 32;
        __half* As = (__half*)smem;   // MT*KP
        __half* Bs = As + MT * KP;    // NN*KP
        const int wid = t >> 6, lane = t & 63;
        const int row0 = ((int)blockIdx.x - pblocks) * MT;
        const int wr = wid & 1, wc = wid >> 1;
        const int lrow = lane & 15, q = lane >> 4;

        floatx4 acc[2][WCT];
#pragma unroll
        for (int rt = 0; rt < 2; ++rt)
#pragma unroll
            for (int ct = 0; ct < WCT; ++ct)
#pragma unroll
                for (int i = 0; i < 4; ++i) acc[rt][ct][i] = 0.f;

        for (int kt = 0; kt < KK; kt += KT) {
            // As: 64 rows x 32 halves = 512 ushort4; 2 per thread
#pragma unroll
            for (int it = 0; it < MT * KT / 4 / 256; ++it) {
                int i4 = it * 256 + t;
                int m = i4 >> 3;
                int kk = (i4 & 7) << 2;
                int gr = row0 + m;
                float4 v = make_float4(0.f, 0.f, 0.f, 0.f);
                if (gr < nrows) v = *(const float4*)(A + (size_t)gr * KK + kt + kk);
                __half h0 = __float2half_rn(v.x), h1 = __float2half_rn(v.y);
                __half h2 = __float2half_rn(v.z), h3 = __float2half_rn(v.w);
                ushort4 u = make_ushort4(*(unsigned short*)&h0, *(unsigned short*)&h1,
                                         *(unsigned short*)&h2, *(unsigned short*)&h3);
                *(ushort4*)(As + m * KP + kk) = u;
            }
            // Bs: 128 rows x 32 halves = 1024 ushort4; 4 per thread
#pragma unroll
            for (int it = 0; it < NN * KT / 4 / 256; ++it) {
                int i4 = it * 256 + t;
                int n = i4 >> 3;
                int kk = (i4 & 7) << 2;
                *(ushort4*)(Bs + n * KP + kk) =
                    *(const ushort4*)(BT + (size_t)n * KK + kt + kk);
            }
            __syncthreads();

            half8 a0 = *(half8*)(As + (wr * 32 + lrow) * KP + q * 8);
            half8 a1 = *(half8*)(As + (wr * 32 + 16 + lrow) * KP + q * 8);
#pragma unroll
            for (int ct = 0; ct < WCT; ++ct) {
                half8 b = *(half8*)(Bs + (wc * (NN / 2) + ct * 16 + lrow) * KP + q * 8);
                acc[0][ct] = __builtin_amdgcn_mfma_f32_16x16x32_f16(a0, b, acc[0][ct], 0, 0, 0);
                acc[1][ct] = __builtin_amdgcn_mfma_f32_16x16x32_f16(a1, b, acc[1][ct], 0, 0, 0);
            }
            __syncthreads();
        }

#pragma unroll
        for (int rt = 0; rt < 2; ++rt)
#pragma unroll
            for (int ct = 0; ct < WCT; ++ct)
#pragma unroll
                for (int r = 0; r < 4; ++r) {
                    int gr = row0 + wr * 32 + rt * 16 + q * 4 + r;
                    if (gr < nrows)
                        C[(size_t)gr * NN + wc * (NN / 2) + ct * 16 + lrow] =
                            __float2half_rn(acc[rt][ct][r]);
                }
    }
}

// ---------------------------------------------------------------- fine scatter + off2 writer
// off2[row] = (start, len) into slotted eb2.
__global__ __launch_bounds__(1024) void fine_scatter_kernel(const int* __restrict__ gcnt,
                                                            const int2* __restrict__ eb1,
                                                            int2* __restrict__ eb2,
                                                            int2* __restrict__ off2,
                                                            int nN) {
    __shared__ int hist[RPB];
    __shared__ int sc[RPB];
    __shared__ int cur[RPB];
    const int b = blockIdx.x;
    const int row0 = b * RPB;
    const int nr = min(RPB, nN - row0);
    const int t = threadIdx.x;
    const int s = b * CAPE;
    const int e = s + min(gcnt[b], CAPE);

    if (t < RPB) hist[t] = 0;
    __syncthreads();
    for (int i = s + t; i < e; i += 1024)
        atomicAdd(&hist[((unsigned)eb1[i].x) >> 17], 1);
    __syncthreads();

    int myc = (t < RPB) ? hist[t] : 0;
    if (t < RPB) sc[t] = myc;
    __syncthreads();
    for (int d = 1; d < RPB; d <<= 1) {
        int add = (t < RPB && t >= d) ? sc[t - d] : 0;
        __syncthreads();
        if (t < RPB) sc[t] += add;
        __syncthreads();
    }
    if (t < RPB) {
        int excl = s + sc[t] - myc;
        cur[t] = excl;
        if (t < nr) off2[row0 + t] = make_int2(excl, myc);
    }
    __syncthreads();

    for (int i = s + t; i < e; i += 1024) {
        int2 ed = eb1[i];
        unsigned x = (unsigned)ed.x;
        int pos = atomicAdd(&cur[x >> 17], 1);
        eb2[pos] = make_int2((int)(x & 0x1FFFF), ed.y);
    }
}

// ---------------------------------------------------------------- FUSED spmm128 + matvec
// Grid-stride wave-per-row. Gather: lane = (edge-subgroup g = lane>>4,
// feature-group fg = lane&15); one dwordx4 load covers 4 edges' rows.
// shfl_xor(16,32) combines subgroups; bias+relu; pack to per-wave LDS
// (plain h2t stores); per-row matvec by W2.
__global__ __launch_bounds__(256) void spmm_fused_kernel(const int2* __restrict__ off2,
                                                         const int2* __restrict__ eb,
                                                         const __half* __restrict__ Y,
                                                         const float* __restrict__ b1,
                                                         const h2t* __restrict__ pk,
                                                         __half* __restrict__ Y2, int nN) {
    __shared__ h2t w2s[64 * 64];  // w2s[kk*64+c] = (W2[2kk][c], W2[2kk+1][c])
    __shared__ h2t hs[4][64];     // per-wave relu'd H1 row, packed pairs
    const int t = threadIdx.x;
#pragma unroll
    for (int i = 0; i < 16; ++i) w2s[i * 256 + t] = pk[i * 256 + t];
    __syncthreads();

    const int wv = t >> 6;
    const int lane = t & 63;
    const int fg = lane & 15;  // feature group: 8 halfs at fg*8
    const int g = lane >> 4;   // edge subgroup 0..3
    const int gw = blockIdx.x * 4 + wv;
    const int nw = gridDim.x * 4;

    for (int row = gw; row < nN; row += nw) {
        float acc[8];
#pragma unroll
        for (int p = 0; p < 8; ++p) acc[p] = 0.f;

        int2 se = off2[row];
        int s = se.x;
        int e1 = s + se.y;
        for (int base = s; base < e1; base += 64) {
            int n = min(64, e1 - base);
            int2 my = (lane < n) ? eb[base + lane] : make_int2(0, 0);
            for (int j = 0; j < n; j += 8) {
                int i0 = j + g;
                int i1 = j + 4 + g;
                // clamp invalid subgroup indices onto edge j (same cache
                // lines, valid source lane); contribution zeroed via val.
                int s0 = (i0 < n) ? i0 : j;
                int s1 = (i1 < n) ? i1 : j;
                // UNCONDITIONAL shuffles (full EXEC); mask results after.
                int c0 = __shfl(my.x, s0);
                int c1 = __shfl(my.x, s1);
                float v0 = __int_as_float(__shfl(my.y, s0));
                float v1 = __int_as_float(__shfl(my.y, s1));
                if (i0 >= n) v0 = 0.f;
                if (i1 >= n) v1 = 0.f;
                half8 y0 = *(const half8*)(Y + ((size_t)c0 << 7) + (fg << 3));
                half8 y1 = *(const half8*)(Y + ((size_t)c1 << 7) + (fg << 3));
#pragma unroll
                for (int p = 0; p < 8; ++p) acc[p] = fmaf(v0, (float)y0[p], acc[p]);
#pragma unroll
                for (int p = 0; p < 8; ++p) acc[p] = fmaf(v1, (float)y1[p], acc[p]);
            }
        }
        // combine the 4 edge-subgroups (lanes differ in bits 4,5 only)
#pragma unroll
        for (int p = 0; p < 8; ++p) acc[p] += __shfl_xor(acc[p], 16);
#pragma unroll
        for (int p = 0; p < 8; ++p) acc[p] += __shfl_xor(acc[p], 32);

        // bias + relu + pack into per-wave LDS. PLAIN element-type (h2t)
        // stores only (barrier-less wave-synchronous handoff).
        if (g == 0) {
            floatx4 ba = *(const floatx4*)(b1 + fg * 8);
            floatx4 bb = *(const floatx4*)(b1 + fg * 8 + 4);
            float f[8];
#pragma unroll
            for (int p = 0; p < 4; ++p) f[p] = fmaxf(acc[p] + ba[p], 0.f);
#pragma unroll
            for (int p = 0; p < 4; ++p) f[4 + p] = fmaxf(acc[4 + p] + bb[p], 0.f);
#pragma unroll
            for (int p = 0; p < 4; ++p) {
                h2t pr;
                pr[0] = (_Float16)f[2 * p];
                pr[1] = (_Float16)f[2 * p + 1];
                hs[wv][fg * 4 + p] = pr;  // hs[wv][i] = features (2i, 2i+1)
            }
        }
        __builtin_amdgcn_sched_barrier(0);  // pin handoff order

        // matvec: o = sum_kk dot2(hs[kk], W2pair[kk][lane])
        // (same-wave DS ordering: no barrier needed)
        float o = 0.f;
#pragma unroll 8
        for (int kk = 0; kk < 64; ++kk) {
            h2t a = hs[wv][kk];           // LDS broadcast (free)
            h2t b = w2s[kk * 64 + lane];  // 2-way bank aliasing (free)
#if __has_builtin(__builtin_amdgcn_fdot2)
            o = __builtin_amdgcn_fdot2(a, b, o, false);
#else
            o = fmaf((float)a[0], (float)b[0], o);
            o = fmaf((float)a[1], (float)b[1], o);
#endif
        }
        Y2[(size_t)row * 64 + lane] = __float2half_rn(o);
    }
}

// ---------------------------------------------------------------- spmm F=64 (final layer)
// Grid-stride wave-per-row, 8-lanes-per-edge dwordx4 gather (one load = 8
// edges' 128B rows); acc[8]; shfl_xor(8,16,32) combines subgroups; lanes
// 0..7 write 256B coalesced fp32.
__global__ __launch_bounds__(256) void spmm_csr64_kernel(const int2* __restrict__ off2,
                                                         const int2* __restrict__ eb,
                                                         const __half* __restrict__ Y,
                                                         const float* __restrict__ bias,
                                                         float* __restrict__ out, int nN) {
    const int lane = threadIdx.x & 63;
    const int fg = lane & 7;  // 8 features at fg*8
    const int g = lane >> 3;  // edge subgroup 0..7
    const int gw = blockIdx.x * 4 + (threadIdx.x >> 6);
    const int nw = gridDim.x * 4;

    for (int row = gw; row < nN; row += nw) {
        float acc[8];
#pragma unroll
        for (int p = 0; p < 8; ++p) acc[p] = 0.f;

        int2 se = off2[row];
        int s = se.x;
        int e1 = s + se.y;
        for (int base = s; base < e1; base += 64) {
            int n = min(64, e1 - base);
            int2 my = (lane < n) ? eb[base + lane] : make_int2(0, 0);
            for (int j = 0; j < n; j += 16) {
                int i0 = j + g;
                int i1 = j + 8 + g;
                int s0 = (i0 < n) ? i0 : j;
                int s1 = (i1 < n) ? i1 : j;
                int c0 = __shfl(my.x, s0);
                int c1 = __shfl(my.x, s1);
                float v0 = __int_as_float(__shfl(my.y, s0));
                float v1 = __int_as_float(__shfl(my.y, s1));
                if (i0 >= n) v0 = 0.f;
                if (i1 >= n) v1 = 0.f;
                half8 y0 = *(const half8*)(Y + ((size_t)c0 << 6) + (fg << 3));
                half8 y1 = *(const half8*)(Y + ((size_t)c1 << 6) + (fg << 3));
#pragma unroll
                for (int p = 0; p < 8; ++p) acc[p] = fmaf(v0, (float)y0[p], acc[p]);
#pragma unroll
                for (int p = 0; p < 8; ++p) acc[p] = fmaf(v1, (float)y1[p], acc[p]);
            }
        }
        // combine the 8 edge-subgroups (lanes differ in bits 3,4,5 only)
#pragma unroll
        for (int p = 0; p < 8; ++p) acc[p] += __shfl_xor(acc[p], 8);
#pragma unroll
        for (int p = 0; p < 8; ++p) acc[p] += __shfl_xor(acc[p], 16);
#pragma unroll
        for (int p = 0; p < 8; ++p) acc[p] += __shfl_xor(acc[p], 32);

        if (g == 0) {
            floatx4 ba = *(const floatx4*)(bias + fg * 8);
            floatx4 bb = *(const floatx4*)(bias + fg * 8 + 4);
            floatx4 o0, o1;
#pragma unroll
            for (int p = 0; p < 4; ++p) o0[p] = acc[p] + ba[p];
#pragma unroll
            for (int p = 0; p < 4; ++p) o1[p] = acc[4 + p] + bb[p];
            float* op = out + (size_t)row * 64 + fg * 8;
            *(floatx4*)op = o0;
            *(floatx4*)(op + 4) = o1;
        }
    }
}

// ---------------------------------------------------------------- fallback atomic path
__global__ __launch_bounds__(256) void init_bias_kernel(float* __restrict__ out,
                                                        const float* __restrict__ bias,
                                                        int fmask, size_t total) {
    size_t i = (size_t)blockIdx.x * 256 + threadIdx.x;
    if (i < total) out[i] = bias[i & fmask];
}

template <int F>
__global__ __launch_bounds__(256) void spmm_atomic_kernel(const int* __restrict__ rows,
                                                          const int* __restrict__ cols,
                                                          const float* __restrict__ vals,
                                                          const __half* __restrict__ Y,
                                                          float* __restrict__ out, int nE) {
    int e = blockIdx.x * 4 + (threadIdx.x >> 6);
    if (e >= nE) return;
    int lane = threadIdx.x & 63;
    int r = rows[e];
    int c = cols[e];
    float v = vals[e];
    if (F == 128) {
        float2 y = __half22float2(*((const __half2*)(Y + (size_t)c * 128) + lane));
        float* op = out + (size_t)r * 128 + lane * 2;
        unsafeAtomicAdd(op, v * y.x);
        unsafeAtomicAdd(op + 1, v * y.y);
    } else {
        float y = __half2float(Y[(size_t)c * F + lane]);
        unsafeAtomicAdd(out + (size_t)r * F + lane, v * y);
    }
}

// ---------------------------------------------------------------- MFMA fp16 GEMM (fallback)
// C[nrows,NN] (fp16) = (RELU_IN ? relu(A) : A)[nrows,KK] (fp32) @ B[KK,NN]
template <int NN, int KK, bool RELU_IN>
__global__ __launch_bounds__(256) void gemm_mfma_kernel(const float* __restrict__ A,
                                                        const __half* __restrict__ BT,
                                                        __half* __restrict__ C, int nrows) {
    constexpr int MT = 64, KT = 64, KP = KT + 8;
    __shared__ __half As[MT * KP];
    __shared__ __half Bs[NN * KP];
    const int tid = threadIdx.x;
    const int wid = tid >> 6, lane = tid & 63;
    const int row0 = blockIdx.x * MT;
    const int wr = wid & 1, wc = wid >> 1;
    constexpr int WCT = NN / 32;
    const int lrow = lane & 15, q = lane >> 4;

    floatx4 acc[2][WCT];
#pragma unroll
    for (int rt = 0; rt < 2; ++rt)
#pragma unroll
        for (int ct = 0; ct < WCT; ++ct)
#pragma unroll
            for (int i = 0; i < 4; ++i) acc[rt][ct][i] = 0.f;

    for (int kt = 0; kt < KK; kt += KT) {
#pragma unroll
        for (int it = 0; it < MT * KT / 4 / 256; ++it) {
            int i4 = it * 256 + tid;
            int m = i4 >> 4;
            int kk = (i4 & 15) << 2;
            int gr = row0 + m;
            float4 v = make_float4(0.f, 0.f, 0.f, 0.f);
            if (gr < nrows) v = *(const float4*)(A + (size_t)gr * KK + kt + kk);
            if (RELU_IN) {
                v.x = fmaxf(v.x, 0.f); v.y = fmaxf(v.y, 0.f);
                v.z = fmaxf(v.z, 0.f); v.w = fmaxf(v.w, 0.f);
            }
            __half h0 = __float2half_rn(v.x), h1 = __float2half_rn(v.y);
            __half h2 = __float2half_rn(v.z), h3 = __float2half_rn(v.w);
            ushort4 u = make_ushort4(*(unsigned short*)&h0, *(unsigned short*)&h1,
                                     *(unsigned short*)&h2, *(unsigned short*)&h3);
            *(ushort4*)(As + m * KP + kk) = u;
        }
#pragma unroll
        for (int it = 0; it < NN * KT / 4 / 256; ++it) {
            int i4 = it * 256 + tid;
            int n = i4 >> 4;
            int kk = (i4 & 15) << 2;
            *(ushort4*)(Bs + n * KP + kk) =
                *(const ushort4*)(BT + (size_t)n * KK + kt + kk);
        }
        __syncthreads();

#pragma unroll
        for (int ks = 0; ks < KT; ks += 32) {
            half8 a0 = *(half8*)(As + (wr * 32 + lrow) * KP + ks + q * 8);
            half8 a1 = *(half8*)(As + (wr * 32 + 16 + lrow) * KP + ks + q * 8);
#pragma unroll
            for (int ct = 0; ct < WCT; ++ct) {
                half8 b = *(half8*)(Bs + (wc * (NN / 2) + ct * 16 + lrow) * KP + ks + q * 8);
                acc[0][ct] = __builtin_amdgcn_mfma_f32_16x16x32_f16(a0, b, acc[0][ct], 0, 0, 0);
                acc[1][ct] = __builtin_amdgcn_mfma_f32_16x16x32_f16(a1, b, acc[1][ct], 0, 0, 0);
            }
        }
        __syncthreads();
    }

#pragma unroll
    for (int rt = 0; rt < 2; ++rt)
#pragma unroll
        for (int ct = 0; ct < WCT; ++ct)
#pragma unroll
            for (int r = 0; r < 4; ++r) {
                int gr = row0 + wr * 32 + rt * 16 + q * 4 + r;
                if (gr < nrows)
                    C[(size_t)gr * NN + wc * (NN / 2) + ct * 16 + lrow] =
                        __float2half_rn(acc[rt][ct][r]);
            }
}

extern "C" void kernel_launch(void* const* d_in, const int* in_sizes, int n_in,
                              void* d_out, int out_size, void* d_ws, size_t ws_size,
                              hipStream_t stream) {
    const float* x    = (const float*)d_in[0];
    const int*   rows = (const int*)d_in[1];
    const int*   cols = (const int*)d_in[2];
    const float* vals = (const float*)d_in[3];
    const float* W1   = (const float*)d_in[4];
    const float* b1   = (const float*)d_in[5];
    const float* W2   = (const float*)d_in[6];
    const float* b2   = (const float*)d_in[7];
    float* out = (float*)d_out;

    const int nN = in_sizes[0] / 256;  // 100000
    const int nE = in_sizes[1];        // 3200000
    const int nB = (nN + RPB - 1) / RPB;

    const int mblocks  = (nN + 63) / 64;
    const int pblocks  = (nE + PCHUNK - 1) / PCHUNK;
    const int sblocks  = min(2048, (nN + 3) / 4);  // grid-stride spmm
    const int eblocks4 = (nE + 3) / 4;

    // ---- fast-path ws layout ----
    char* w = (char*)d_ws;
    __half* Y1h  = (__half*)w;  w += (size_t)nN * 128 * 2;
    __half* Y2h  = (__half*)w;  w += (size_t)nN * 64 * 2;
    __half* W1T  = (__half*)w;  w += (size_t)256 * 128 * 2;
    h2t*    pk   = (h2t*)w;     w += (size_t)4096 * 4;
    int2*   off2 = (int2*)w;    w += (size_t)nN * 8;
    int*    gcnt = (int*)w;     w += (size_t)NB_MAX * 4;
    int2*   eb1  = (int2*)w;    w += (size_t)nB * CAPE * 8;
    int2*   eb2  = (int2*)w;    w += (size_t)nB * CAPE * 8;
    size_t need = (size_t)(w - (char*)d_ws);

    // slot safety: mean bucket load + ~17 sigma must fit in CAPE
    const bool slots_ok = (nE / nB) <= (CAPE - 1540);

    if (ws_size >= need && nN <= (1 << 17) && nB <= NB_MAX && slots_ok) {
        // ---- fast path (5 dispatches) ----
        prep_weights_kernel<<<(256 * 128 + 4096 + NB_MAX + 255) / 256, 256, 0, stream>>>(
            W1, W2, W1T, pk, gcnt);

        // gemm1 || partition (independent; partition blocks first so
        // fine_scatter's dependency clears earliest). Dynamic LDS 15360 B.
        gemm_part_kernel<<<pblocks + mblocks, 256, (64 + 128) * 40 * 2, stream>>>(
            x, W1T, Y1h, nN, rows, cols, vals, gcnt, eb1, nE, nB, pblocks);

        fine_scatter_kernel<<<nB, 1024, 0, stream>>>(gcnt, eb1, eb2, off2, nN);

        // Y2 = fp16(relu(b1 + spmm(Y1)) @ W2)   [fused]
        spmm_fused_kernel<<<sblocks, 256, 0, stream>>>(off2, eb2, Y1h, b1, pk, Y2h, nN);
        // out = b2 + spmm(Y2)
        spmm_csr64_kernel<<<sblocks, 256, 0, stream>>>(off2, eb2, Y2h, b2, out, nN);
    } else {
        // ---- fallback: atomic path (own ws layout) ----
        char* v = (char*)d_ws;
        __half* fY1h = (__half*)v;  v += (size_t)nN * 128 * 2;
        float*  fH1  = (float*)v;   v += (size_t)nN * 128 * 4;
        __half* fW1T = (__half*)v;  v += (size_t)256 * 128 * 2;
        __half* fW2T = (__half*)v;  v += (size_t)128 * 64 * 2;

        transpose_w_kernel<<<(256 * 128 + 255) / 256, 256, 0, stream>>>(W1, fW1T, 256, 128);
        transpose_w_kernel<<<(128 * 64 + 255) / 256, 256, 0, stream>>>(W2, fW2T, 128, 64);
        gemm_mfma_kernel<128, 256, false><<<mblocks, 256, 0, stream>>>(x, fW1T, fY1h, nN);
        size_t totH1 = (size_t)nN * 128;
        init_bias_kernel<<<(int)((totH1 + 255) / 256), 256, 0, stream>>>(fH1, b1, 127, totH1);
        spmm_atomic_kernel<128><<<eblocks4, 256, 0, stream>>>(rows, cols, vals, fY1h, fH1, nE);
        gemm_mfma_kernel<64, 128, true><<<mblocks, 256, 0, stream>>>(fH1, fW2T, fY1h, nN);
        size_t totOut = (size_t)nN * 64;
        init_bias_kernel<<<(int)((totOut + 255) / 256), 256, 0, stream>>>(out, b2, 63, totOut);
        spmm_atomic_kernel<64><<<eblocks4, 256, 0, stream>>>(rows, cols, vals, fY1h, out, nE);
    }
}